// Round 2
// baseline (317.836 us; speedup 1.0000x reference)
//
#include <hip/hip_runtime.h>

#define NB   4
#define SEQ  4096
#define CIN  128
#define C4D  32
#define OUTC 128

typedef __attribute__((ext_vector_type(8))) short bf16x8;
typedef __attribute__((ext_vector_type(4))) short bf16x4;
typedef __attribute__((ext_vector_type(4))) float f32x4;

__device__ __forceinline__ short f2bf(float f) {
  union { float f; unsigned u; } v; v.f = f;
  unsigned r = v.u + 0x7FFFu + ((v.u >> 16) & 1u);
  return (short)(r >> 16);
}

__device__ __forceinline__ f32x4 mfma16(bf16x8 a, bf16x8 b, f32x4 c) {
  return __builtin_amdgcn_mfma_f32_16x16x32_bf16(a, b, c, 0, 0, 0);
}

// ---------------------------------------------------------------------------
// Kernel 1: fold value-path weights.  WfT[u][c] = sum_o wv[o][c]*weight[o][u]
// bfu[u] = sum_o bv[o]*weight[o][u];  also cast wq/wk to bf16.
// ---------------------------------------------------------------------------
__global__ void k_fuse(const float* __restrict__ wq, const float* __restrict__ wk,
                       const float* __restrict__ wv, const float* __restrict__ weight,
                       const float* __restrict__ bv,
                       short* __restrict__ wqb, short* __restrict__ wkb,
                       short* __restrict__ wfT, float* __restrict__ bfu) {
  int u = blockIdx.x, c = threadIdx.x;
  float acc = 0.f;
  for (int o = 0; o < OUTC; ++o) acc += wv[o * CIN + c] * weight[o * OUTC + u];
  wfT[u * CIN + c] = f2bf(acc);
  if (u < C4D) {
    wqb[u * CIN + c] = f2bf(wq[u * CIN + c]);
    wkb[u * CIN + c] = f2bf(wk[u * CIN + c]);
  }
  if (c == 0) {
    float a = 0.f;
    for (int o = 0; o < OUTC; ++o) a += bv[o] * weight[o * OUTC + u];
    bfu[u] = a;
  }
}

// ---------------------------------------------------------------------------
// Kernel 2: projections. Per wave: 16 positions. q[32], k[32], support[128].
// q/k stored [p][32] bf16; support stored transposed supT[b][u][s] bf16.
// ---------------------------------------------------------------------------
__global__ __launch_bounds__(256) void k_proj(
    const float* __restrict__ x, const float* __restrict__ bq, const float* __restrict__ bk,
    const short* __restrict__ wqb, const short* __restrict__ wkb,
    const short* __restrict__ wfT, const float* __restrict__ bfu,
    short* __restrict__ qb, short* __restrict__ kb, short* __restrict__ supT) {
  const int wid = threadIdx.x >> 6, lane = threadIdx.x & 63;
  const int lo = lane & 15, g = lane >> 4;
  const int p0 = blockIdx.x * 64 + wid * 16;

  f32x4 aq[2] = {}, ak[2] = {}, as_[8] = {};

#pragma unroll
  for (int kk = 0; kk < 4; ++kk) {
    const float* xp = x + (size_t)(p0 + lo) * CIN + kk * 32 + g * 8;
    float4 xa = *(const float4*)xp;
    float4 xb = *(const float4*)(xp + 4);
    bf16x8 af;
    af[0] = f2bf(xa.x); af[1] = f2bf(xa.y); af[2] = f2bf(xa.z); af[3] = f2bf(xa.w);
    af[4] = f2bf(xb.x); af[5] = f2bf(xb.y); af[6] = f2bf(xb.z); af[7] = f2bf(xb.w);
#pragma unroll
    for (int n = 0; n < 2; ++n) {
      bf16x8 bq_ = *(const bf16x8*)(wqb + (size_t)(n * 16 + lo) * CIN + kk * 32 + g * 8);
      aq[n] = mfma16(af, bq_, aq[n]);
      bf16x8 bk_ = *(const bf16x8*)(wkb + (size_t)(n * 16 + lo) * CIN + kk * 32 + g * 8);
      ak[n] = mfma16(af, bk_, ak[n]);
    }
#pragma unroll
    for (int n = 0; n < 8; ++n) {
      bf16x8 bs = *(const bf16x8*)(wfT + (size_t)(n * 16 + lo) * CIN + kk * 32 + g * 8);
      as_[n] = mfma16(af, bs, as_[n]);
    }
  }

#pragma unroll
  for (int n = 0; n < 2; ++n) {
    float bqv = bq[n * 16 + lo], bkv = bk[n * 16 + lo];
#pragma unroll
    for (int r = 0; r < 4; ++r) {
      int p = p0 + 4 * g + r;
      qb[(size_t)p * C4D + n * 16 + lo] = f2bf(aq[n][r] + bqv);
      kb[(size_t)p * C4D + n * 16 + lo] = f2bf(ak[n][r] + bkv);
    }
  }
#pragma unroll
  for (int n = 0; n < 8; ++n) {
    int u = n * 16 + lo;
    float bvv = bfu[u];
#pragma unroll
    for (int r = 0; r < 4; ++r) {
      int p = p0 + 4 * g + r;
      supT[(size_t)(p >> 12) * (OUTC * SEQ) + (size_t)u * SEQ + (p & (SEQ - 1))] =
          f2bf(as_[n][r] + bvv);
    }
  }
}

// ---------------------------------------------------------------------------
// Kernel 3: flash attention over j with online softmax.
// Wave owns 16 i-rows. Scores: D'[j][i] = mfma(Q_frag, K_frag) -> i on l&15.
// P stays lane-local for the PV A-fragment; V loaded with matching j-slots.
// ---------------------------------------------------------------------------
__global__ __launch_bounds__(256) void k_attn(
    const short* __restrict__ qb, const short* __restrict__ kb,
    const short* __restrict__ supT, const float* __restrict__ bias,
    float* __restrict__ out) {
  const int wid = threadIdx.x >> 6, lane = threadIdx.x & 63;
  const int lo = lane & 15, g = lane >> 4;
  const int blk = blockIdx.x;
  const int b = blk >> 6;
  const int i0 = (blk & 63) * 64 + wid * 16;
  const short* qB = qb + (size_t)b * SEQ * C4D;
  const short* kB = kb + (size_t)b * SEQ * C4D;
  const short* vB = supT + (size_t)b * OUTC * SEQ;

  bf16x8 kf = *(const bf16x8*)(kB + (size_t)(i0 + lo) * C4D + g * 8);
  f32x4 o[8] = {};
  float mrow = -3e38f, lrow = 0.f;
  const f32x4 zf = {0.f, 0.f, 0.f, 0.f};

  for (int j0 = 0; j0 < SEQ; j0 += 32) {
    bf16x8 qf0 = *(const bf16x8*)(qB + (size_t)(j0 + lo) * C4D + g * 8);
    bf16x8 qf1 = *(const bf16x8*)(qB + (size_t)(j0 + 16 + lo) * C4D + g * 8);
    f32x4 s0 = mfma16(qf0, kf, zf);
    f32x4 s1 = mfma16(qf1, kf, zf);

    float tm = fmaxf(fmaxf(fmaxf(s0[0], s0[1]), fmaxf(s0[2], s0[3])),
                     fmaxf(fmaxf(s1[0], s1[1]), fmaxf(s1[2], s1[3])));
    tm = fmaxf(tm, __shfl_xor(tm, 16, 64));
    tm = fmaxf(tm, __shfl_xor(tm, 32, 64));
    float mnew = fmaxf(mrow, tm);
    float scale = __expf(mrow - mnew);
    float p[8];
#pragma unroll
    for (int r = 0; r < 4; ++r) {
      p[r]     = __expf(s0[r] - mnew);
      p[4 + r] = __expf(s1[r] - mnew);
    }
    float ps = p[0] + p[1] + p[2] + p[3] + p[4] + p[5] + p[6] + p[7];
    ps += __shfl_xor(ps, 16, 64);
    ps += __shfl_xor(ps, 32, 64);
    lrow = lrow * scale + ps;
    mrow = mnew;

    bf16x8 pf;
#pragma unroll
    for (int r = 0; r < 8; ++r) pf[r] = f2bf(p[r]);

    float sc[4];
#pragma unroll
    for (int r = 0; r < 4; ++r) sc[r] = __shfl(scale, 4 * g + r, 64);
#pragma unroll
    for (int n = 0; n < 8; ++n) {
#pragma unroll
      for (int r = 0; r < 4; ++r) o[n][r] *= sc[r];
    }

#pragma unroll
    for (int n = 0; n < 8; ++n) {
      const short* vp = vB + (size_t)(n * 16 + lo) * SEQ + j0 + 4 * g;
      bf16x4 v0 = *(const bf16x4*)vp;
      bf16x4 v1 = *(const bf16x4*)(vp + 16);
      bf16x8 vf = {v0[0], v0[1], v0[2], v0[3], v1[0], v1[1], v1[2], v1[3]};
      o[n] = mfma16(pf, vf, o[n]);
    }
  }

  float li[4];
#pragma unroll
  for (int r = 0; r < 4; ++r) li[r] = 1.f / __shfl(lrow, 4 * g + r, 64);
#pragma unroll
  for (int n = 0; n < 8; ++n) {
    float bu = bias[n * 16 + lo];
#pragma unroll
    for (int r = 0; r < 4; ++r) {
      out[(size_t)(b * SEQ + i0 + 4 * g + r) * OUTC + n * 16 + lo] = o[n][r] * li[r] + bu;
    }
  }
}

// ---------------------------------------------------------------------------
extern "C" void kernel_launch(void* const* d_in, const int* in_sizes, int n_in,
                              void* d_out, int out_size, void* d_ws, size_t ws_size,
                              hipStream_t stream) {
  (void)in_sizes; (void)n_in; (void)out_size; (void)ws_size;
  const float* x      = (const float*)d_in[0];
  const float* weight = (const float*)d_in[1];
  const float* bias   = (const float*)d_in[2];
  const float* wq     = (const float*)d_in[3];
  const float* bq     = (const float*)d_in[4];
  const float* wk     = (const float*)d_in[5];
  const float* bk     = (const float*)d_in[6];
  const float* wv     = (const float*)d_in[7];
  const float* bv     = (const float*)d_in[8];
  float* out = (float*)d_out;

  char* ws = (char*)d_ws;
  short* qbuf = (short*)(ws);                                   // 1 MiB
  short* kbuf = (short*)(ws + ((size_t)1 << 20));               // 1 MiB
  short* supT = (short*)(ws + ((size_t)2 << 20));               // 4 MiB
  short* wqb  = (short*)(ws + ((size_t)6 << 20));               // 8 KiB
  short* wkb  = (short*)(ws + ((size_t)6 << 20) + 8192);        // 8 KiB
  short* wfT  = (short*)(ws + ((size_t)6 << 20) + 16384);       // 32 KiB
  float* bfu  = (float*)(ws + ((size_t)6 << 20) + 49152);       // 512 B

  hipLaunchKernelGGL(k_fuse, dim3(OUTC), dim3(CIN), 0, stream,
                     wq, wk, wv, weight, bv, wqb, wkb, wfT, bfu);
  hipLaunchKernelGGL(k_proj, dim3(NB * SEQ / 64), dim3(256), 0, stream,
                     x, bq, bk, wqb, wkb, wfT, bfu, qbuf, kbuf, supT);
  hipLaunchKernelGGL(k_attn, dim3(NB * SEQ / 64), dim3(256), 0, stream,
                     qbuf, kbuf, supT, bias, out);
}

// Round 4
// 267.739 us; speedup vs baseline: 1.1871x; 1.1871x over previous
//
#include <hip/hip_runtime.h>

#define NB   4
#define SEQ  4096
#define CIN  128
#define C4D  32
#define OUTC 128

typedef __attribute__((ext_vector_type(8))) short bf16x8;
typedef __attribute__((ext_vector_type(4))) short bf16x4;
typedef __attribute__((ext_vector_type(4))) float f32x4;

__device__ __forceinline__ short f2bf(float f) {
  union { float f; unsigned u; } v; v.f = f;
  unsigned r = v.u + 0x7FFFu + ((v.u >> 16) & 1u);
  return (short)(r >> 16);
}

__device__ __forceinline__ f32x4 mfma16(bf16x8 a, bf16x8 b, f32x4 c) {
  return __builtin_amdgcn_mfma_f32_16x16x32_bf16(a, b, c, 0, 0, 0);
}

// ---------------------------------------------------------------------------
// Kernel 1: fold value-path weights.  WfT[u][c] = sum_o wv[o][c]*weight[o][u]
// bfu[u] = sum_o bv[o]*weight[o][u];  also cast wq/wk to bf16.
// ---------------------------------------------------------------------------
__global__ void k_fuse(const float* __restrict__ wq, const float* __restrict__ wk,
                       const float* __restrict__ wv, const float* __restrict__ weight,
                       const float* __restrict__ bv,
                       short* __restrict__ wqb, short* __restrict__ wkb,
                       short* __restrict__ wfT, float* __restrict__ bfu) {
  int u = blockIdx.x, c = threadIdx.x;
  float acc = 0.f;
  for (int o = 0; o < OUTC; ++o) acc += wv[o * CIN + c] * weight[o * OUTC + u];
  wfT[u * CIN + c] = f2bf(acc);
  if (u < C4D) {
    wqb[u * CIN + c] = f2bf(wq[u * CIN + c]);
    wkb[u * CIN + c] = f2bf(wk[u * CIN + c]);
  }
  if (c == 0) {
    float a = 0.f;
    for (int o = 0; o < OUTC; ++o) a += bv[o] * weight[o * OUTC + u];
    bfu[u] = a;
  }
}

// ---------------------------------------------------------------------------
// Kernel 2: projections. Per wave: 16 positions. q[32], k[32], support[128].
// q/k stored [p][32] bf16; support stored transposed supT[b][u][s] bf16.
// ---------------------------------------------------------------------------
__global__ __launch_bounds__(256) void k_proj(
    const float* __restrict__ x, const float* __restrict__ bq, const float* __restrict__ bk,
    const short* __restrict__ wqb, const short* __restrict__ wkb,
    const short* __restrict__ wfT, const float* __restrict__ bfu,
    short* __restrict__ qb, short* __restrict__ kb, short* __restrict__ supT) {
  const int wid = threadIdx.x >> 6, lane = threadIdx.x & 63;
  const int lo = lane & 15, g = lane >> 4;
  const int p0 = blockIdx.x * 64 + wid * 16;

  f32x4 aq[2] = {}, ak[2] = {}, as_[8] = {};

#pragma unroll
  for (int kk = 0; kk < 4; ++kk) {
    const float* xp = x + (size_t)(p0 + lo) * CIN + kk * 32 + g * 8;
    float4 xa = *(const float4*)xp;
    float4 xb = *(const float4*)(xp + 4);
    bf16x8 af;
    af[0] = f2bf(xa.x); af[1] = f2bf(xa.y); af[2] = f2bf(xa.z); af[3] = f2bf(xa.w);
    af[4] = f2bf(xb.x); af[5] = f2bf(xb.y); af[6] = f2bf(xb.z); af[7] = f2bf(xb.w);
#pragma unroll
    for (int n = 0; n < 2; ++n) {
      bf16x8 bq_ = *(const bf16x8*)(wqb + (size_t)(n * 16 + lo) * CIN + kk * 32 + g * 8);
      aq[n] = mfma16(af, bq_, aq[n]);
      bf16x8 bk_ = *(const bf16x8*)(wkb + (size_t)(n * 16 + lo) * CIN + kk * 32 + g * 8);
      ak[n] = mfma16(af, bk_, ak[n]);
    }
#pragma unroll
    for (int n = 0; n < 8; ++n) {
      bf16x8 bs = *(const bf16x8*)(wfT + (size_t)(n * 16 + lo) * CIN + kk * 32 + g * 8);
      as_[n] = mfma16(af, bs, as_[n]);
    }
  }

#pragma unroll
  for (int n = 0; n < 2; ++n) {
    float bqv = bq[n * 16 + lo], bkv = bk[n * 16 + lo];
#pragma unroll
    for (int r = 0; r < 4; ++r) {
      int p = p0 + 4 * g + r;
      qb[(size_t)p * C4D + n * 16 + lo] = f2bf(aq[n][r] + bqv);
      kb[(size_t)p * C4D + n * 16 + lo] = f2bf(ak[n][r] + bkv);
    }
  }
#pragma unroll
  for (int n = 0; n < 8; ++n) {
    int u = n * 16 + lo;
    float bvv = bfu[u];
#pragma unroll
    for (int r = 0; r < 4; ++r) {
      int p = p0 + 4 * g + r;
      supT[(size_t)(p >> 12) * (OUTC * SEQ) + (size_t)u * SEQ + (p & (SEQ - 1))] =
          f2bf(as_[n][r] + bvv);
    }
  }
}

// ---------------------------------------------------------------------------
// Kernel 3: attention. 4-way j-split across the block's 4 waves (occupancy),
// R2-verbatim online softmax per wave, max-aware LDS combine.
// Wave owns 16 i-rows; scores D[j][i]: i on l&15, j on 4*(l>>4)+r.
// ---------------------------------------------------------------------------
__global__ __launch_bounds__(256) void k_attn(
    const short* __restrict__ qb, const short* __restrict__ kb,
    const short* __restrict__ supT, const float* __restrict__ bias,
    float* __restrict__ out) {
  const int wid = threadIdx.x >> 6, lane = threadIdx.x & 63;
  const int lo = lane & 15, g = lane >> 4;
  const int b = blockIdx.x >> 8;
  const int i0 = (blockIdx.x & 255) * 16;
  const short* qB = qb + (size_t)b * SEQ * C4D;
  const short* kB = kb + (size_t)b * SEQ * C4D;
  const short* vB = supT + (size_t)b * OUTC * SEQ;

  __shared__ float m_lds[4][16];
  __shared__ float l_lds[4][16];
  __shared__ float o_lds[4][16][OUTC + 4];

  bf16x8 kf = *(const bf16x8*)(kB + (size_t)(i0 + lo) * C4D + g * 8);
  f32x4 o[8] = {};
  float mrow = -3e38f, lrow = 0.f;
  const f32x4 zf = {0.f, 0.f, 0.f, 0.f};

  for (int j0 = wid * 32; j0 < SEQ; j0 += 128) {
    bf16x8 qf0 = *(const bf16x8*)(qB + (size_t)(j0 + lo) * C4D + g * 8);
    bf16x8 qf1 = *(const bf16x8*)(qB + (size_t)(j0 + 16 + lo) * C4D + g * 8);
    f32x4 s0 = mfma16(qf0, kf, zf);
    f32x4 s1 = mfma16(qf1, kf, zf);

    float tm = fmaxf(fmaxf(fmaxf(s0[0], s0[1]), fmaxf(s0[2], s0[3])),
                     fmaxf(fmaxf(s1[0], s1[1]), fmaxf(s1[2], s1[3])));
    tm = fmaxf(tm, __shfl_xor(tm, 16, 64));
    tm = fmaxf(tm, __shfl_xor(tm, 32, 64));
    float mnew = fmaxf(mrow, tm);
    float scale = __expf(mrow - mnew);
    float p[8];
#pragma unroll
    for (int r = 0; r < 4; ++r) {
      p[r]     = __expf(s0[r] - mnew);
      p[4 + r] = __expf(s1[r] - mnew);
    }
    float ps = p[0] + p[1] + p[2] + p[3] + p[4] + p[5] + p[6] + p[7];
    ps += __shfl_xor(ps, 16, 64);
    ps += __shfl_xor(ps, 32, 64);
    lrow = lrow * scale + ps;
    mrow = mnew;

    bf16x8 pf;
#pragma unroll
    for (int r = 0; r < 8; ++r) pf[r] = f2bf(p[r]);

    float sc[4];
#pragma unroll
    for (int r = 0; r < 4; ++r) sc[r] = __shfl(scale, 4 * g + r, 64);
#pragma unroll
    for (int n = 0; n < 8; ++n) {
#pragma unroll
      for (int r = 0; r < 4; ++r) o[n][r] *= sc[r];
    }

#pragma unroll
    for (int n = 0; n < 8; ++n) {
      const short* vp = vB + (size_t)(n * 16 + lo) * SEQ + j0 + 4 * g;
      bf16x4 v0 = *(const bf16x4*)vp;
      bf16x4 v1 = *(const bf16x4*)(vp + 16);
      bf16x8 vf = {v0[0], v0[1], v0[2], v0[3], v1[0], v1[1], v1[2], v1[3]};
      o[n] = mfma16(pf, vf, o[n]);
    }
  }

  // Per-wave (m, l) for rows i = lo; o partial in D layout [i=4g+r][u=n*16+lo].
  if (lane < 16) { m_lds[wid][lo] = mrow; l_lds[wid][lo] = lrow; }
#pragma unroll
  for (int n = 0; n < 8; ++n)
#pragma unroll
    for (int r = 0; r < 4; ++r)
      o_lds[wid][4 * g + r][n * 16 + lo] = o[n][r];

  __syncthreads();

  // Max-aware combine of 4 wave-partials; normalize; add bias; store.
  const int row = threadIdx.x >> 4;          // i offset 0..15
  const int c0 = (threadIdx.x & 15) * 8;     // u offset 0..120
  float m0 = m_lds[0][row], m1 = m_lds[1][row];
  float m2 = m_lds[2][row], m3 = m_lds[3][row];
  float M = fmaxf(fmaxf(m0, m1), fmaxf(m2, m3));
  float e0 = __expf(m0 - M), e1 = __expf(m1 - M);
  float e2 = __expf(m2 - M), e3 = __expf(m3 - M);
  float lsum = e0 * l_lds[0][row] + e1 * l_lds[1][row] +
               e2 * l_lds[2][row] + e3 * l_lds[3][row];
  float linv = 1.f / lsum;
  float* op = out + (size_t)(b * SEQ + i0 + row) * OUTC;
#pragma unroll
  for (int e = 0; e < 8; ++e) {
    int c = c0 + e;
    float s = e0 * o_lds[0][row][c] + e1 * o_lds[1][row][c] +
              e2 * o_lds[2][row][c] + e3 * o_lds[3][row][c];
    op[c] = s * linv + bias[c];
  }
}

// ---------------------------------------------------------------------------
extern "C" void kernel_launch(void* const* d_in, const int* in_sizes, int n_in,
                              void* d_out, int out_size, void* d_ws, size_t ws_size,
                              hipStream_t stream) {
  (void)in_sizes; (void)n_in; (void)out_size; (void)ws_size;
  const float* x      = (const float*)d_in[0];
  const float* weight = (const float*)d_in[1];
  const float* bias   = (const float*)d_in[2];
  const float* wq     = (const float*)d_in[3];
  const float* bq     = (const float*)d_in[4];
  const float* wk     = (const float*)d_in[5];
  const float* bk     = (const float*)d_in[6];
  const float* wv     = (const float*)d_in[7];
  const float* bv     = (const float*)d_in[8];
  float* out = (float*)d_out;

  char* ws = (char*)d_ws;
  short* qbuf = (short*)(ws);                                   // 1 MiB
  short* kbuf = (short*)(ws + ((size_t)1 << 20));               // 1 MiB
  short* supT = (short*)(ws + ((size_t)2 << 20));               // 4 MiB
  short* wqb  = (short*)(ws + ((size_t)6 << 20));               // 8 KiB
  short* wkb  = (short*)(ws + ((size_t)6 << 20) + 8192);        // 8 KiB
  short* wfT  = (short*)(ws + ((size_t)6 << 20) + 16384);       // 32 KiB
  float* bfu  = (float*)(ws + ((size_t)6 << 20) + 49152);       // 512 B

  hipLaunchKernelGGL(k_fuse, dim3(OUTC), dim3(CIN), 0, stream,
                     wq, wk, wv, weight, bv, wqb, wkb, wfT, bfu);
  hipLaunchKernelGGL(k_proj, dim3(NB * SEQ / 64), dim3(256), 0, stream,
                     x, bq, bk, wqb, wkb, wfT, bfu, qbuf, kbuf, supT);
  hipLaunchKernelGGL(k_attn, dim3(NB * SEQ / 16), dim3(256), 0, stream,
                     qbuf, kbuf, supT, bias, out);
}

// Round 5
// 81.623 us; speedup vs baseline: 3.8940x; 3.2802x over previous
//
#include <hip/hip_runtime.h>

#define NB   4
#define SEQ  4096
#define CIN  128
#define C4D  32
#define OUTC 128
#define NTILE 64   // 32-j tiles per j-half (2048/32)

typedef __attribute__((ext_vector_type(8))) short bf16x8;
typedef __attribute__((ext_vector_type(4))) float f32x4;

__device__ __forceinline__ short f2bf(float f) {
  union { float f; unsigned u; } v; v.f = f;
  unsigned r = v.u + 0x7FFFu + ((v.u >> 16) & 1u);
  return (short)(r >> 16);
}

__device__ __forceinline__ f32x4 mfma16(bf16x8 a, bf16x8 b, f32x4 c) {
  return __builtin_amdgcn_mfma_f32_16x16x32_bf16(a, b, c, 0, 0, 0);
}

// ---------------------------------------------------------------------------
// Kernel 1: fold value-path weights (unchanged).
// ---------------------------------------------------------------------------
__global__ void k_fuse(const float* __restrict__ wq, const float* __restrict__ wk,
                       const float* __restrict__ wv, const float* __restrict__ weight,
                       const float* __restrict__ bv,
                       short* __restrict__ wqb, short* __restrict__ wkb,
                       short* __restrict__ wfT, float* __restrict__ bfu) {
  int u = blockIdx.x, c = threadIdx.x;
  float acc = 0.f;
  for (int o = 0; o < OUTC; ++o) acc += wv[o * CIN + c] * weight[o * OUTC + u];
  wfT[u * CIN + c] = f2bf(acc);
  if (u < C4D) {
    wqb[u * CIN + c] = f2bf(wq[u * CIN + c]);
    wkb[u * CIN + c] = f2bf(wk[u * CIN + c]);
  }
  if (c == 0) {
    float a = 0.f;
    for (int o = 0; o < OUTC; ++o) a += bv[o] * weight[o * OUTC + u];
    bfu[u] = a;
  }
}

// ---------------------------------------------------------------------------
// Kernel 2: projections. q stored in fragment-linear QL tiles (1024 sh/tile),
// k row-major [p][32], support in fragment-linear VF tiles (4096 sh/tile).
// VF short idx within tile: n*512 + g*128 + lo*8 + jh*4 + r
//   for element V[j = 32t + 4g + r + 16jh][u = n*16 + lo]
// QL short idx within tile: jh*512 + (c>>3)*128 + (j&15)*8 + (c&7)
// ---------------------------------------------------------------------------
__global__ __launch_bounds__(256) void k_proj(
    const float* __restrict__ x, const float* __restrict__ bq, const float* __restrict__ bk,
    const short* __restrict__ wqb, const short* __restrict__ wkb,
    const short* __restrict__ wfT, const float* __restrict__ bfu,
    short* __restrict__ ql, short* __restrict__ kb, short* __restrict__ vfb) {
  const int wid = threadIdx.x >> 6, lane = threadIdx.x & 63;
  const int lo = lane & 15, g = lane >> 4;
  const int p0 = blockIdx.x * 64 + wid * 16;

  f32x4 aq[2] = {}, ak[2] = {}, as_[8] = {};

#pragma unroll
  for (int kk = 0; kk < 4; ++kk) {
    const float* xp = x + (size_t)(p0 + lo) * CIN + kk * 32 + g * 8;
    float4 xa = *(const float4*)xp;
    float4 xb = *(const float4*)(xp + 4);
    bf16x8 af;
    af[0] = f2bf(xa.x); af[1] = f2bf(xa.y); af[2] = f2bf(xa.z); af[3] = f2bf(xa.w);
    af[4] = f2bf(xb.x); af[5] = f2bf(xb.y); af[6] = f2bf(xb.z); af[7] = f2bf(xb.w);
#pragma unroll
    for (int n = 0; n < 2; ++n) {
      bf16x8 bq_ = *(const bf16x8*)(wqb + (size_t)(n * 16 + lo) * CIN + kk * 32 + g * 8);
      aq[n] = mfma16(af, bq_, aq[n]);
      bf16x8 bk_ = *(const bf16x8*)(wkb + (size_t)(n * 16 + lo) * CIN + kk * 32 + g * 8);
      ak[n] = mfma16(af, bk_, ak[n]);
    }
#pragma unroll
    for (int n = 0; n < 8; ++n) {
      bf16x8 bs = *(const bf16x8*)(wfT + (size_t)(n * 16 + lo) * CIN + kk * 32 + g * 8);
      as_[n] = mfma16(af, bs, as_[n]);
    }
  }

#pragma unroll
  for (int n = 0; n < 2; ++n) {
    float bqv = bq[n * 16 + lo], bkv = bk[n * 16 + lo];
    int u = n * 16 + lo;
#pragma unroll
    for (int r = 0; r < 4; ++r) {
      int p = p0 + 4 * g + r;
      int bb = p >> 12, s = p & (SEQ - 1);
      ql[(size_t)bb * (SEQ * 32) + (size_t)(s >> 5) * 1024 + ((s >> 4) & 1) * 512 +
         (u >> 3) * 128 + (s & 15) * 8 + (u & 7)] = f2bf(aq[n][r] + bqv);
      kb[(size_t)p * C4D + u] = f2bf(ak[n][r] + bkv);
    }
  }
#pragma unroll
  for (int n = 0; n < 8; ++n) {
    int u = n * 16 + lo;
    float bvv = bfu[u];
#pragma unroll
    for (int r = 0; r < 4; ++r) {
      int p = p0 + 4 * g + r;
      int bb = p >> 12, s = p & (SEQ - 1);
      vfb[(size_t)bb * (SEQ * 128) + (size_t)(s >> 5) * 4096 + (u >> 4) * 512 +
          ((s >> 2) & 3) * 128 + (u & 15) * 8 + ((s >> 4) & 1) * 4 + (s & 3)] =
          f2bf(as_[n][r] + bvv);
    }
  }
}

// ---------------------------------------------------------------------------
// Kernel 3: attention. Block = 8 waves / 64 i-rows. Waves 0-3: j in [0,2048),
// waves 4-7: j in [2048,4096); wave (wid&3) owns i-sub (wid&3). Each 4-wave
// group stages its 32-j tile (V 8KB + Q 2KB, fragment-linear) into LDS,
// double-buffered, reg-staged. Online softmax per wave; max-aware 2-group
// merge through LDS at the end.
// ---------------------------------------------------------------------------
__global__ __launch_bounds__(512) void k_attn(
    const short* __restrict__ ql, const short* __restrict__ kb,
    const short* __restrict__ vfb, const float* __restrict__ bias,
    float* __restrict__ out) {
  const int tid = threadIdx.x;
  const int wid = tid >> 6, lane = tid & 63;
  const int lo = lane & 15, g = lane >> 4;
  const int wid4 = wid & 3, grp = wid >> 2;
  const int b = blockIdx.x >> 6;
  const int i0 = (blockIdx.x & 63) * 64;
  const int iw = i0 + wid4 * 16;

  __shared__ __align__(16) char smem[40960];
  short* T = (short*)smem;
  // v tiles: 4 x 4096 shorts; q tiles: 4 x 1024 shorts after them.

  const size_t vbase = (size_t)b * (SEQ * 128) + (size_t)grp * (NTILE * 4096);
  const size_t qbase = (size_t)b * (SEQ * 32) + (size_t)grp * (NTILE * 1024);

  bf16x8 kf = *(const bf16x8*)(kb + (size_t)(b * SEQ + iw + lo) * C4D + g * 8);

  f32x4 o[8] = {};
  float mrow = -3e38f, lrow = 0.f;
  const f32x4 zf = {0.f, 0.f, 0.f, 0.f};

  bf16x8 rv0 = {}, rv1 = {}, rq = {};

  // prologue: stage tile 0
  {
    const short* sv = vfb + vbase + wid4 * 1024 + lane * 8;
    rv0 = *(const bf16x8*)(sv);
    rv1 = *(const bf16x8*)(sv + 512);
    if (wid4 >= 2) rq = *(const bf16x8*)(ql + qbase + (wid4 - 2) * 512 + lane * 8);
    short* vd = T + grp * 2 * 4096;
    *(bf16x8*)(vd + wid4 * 1024 + lane * 8) = rv0;
    *(bf16x8*)(vd + wid4 * 1024 + 512 + lane * 8) = rv1;
    if (wid4 >= 2) *(bf16x8*)(T + 16384 + grp * 2 * 1024 + (wid4 - 2) * 512 + lane * 8) = rq;
  }
  __syncthreads();

  for (int t = 0; t < NTILE; ++t) {
    const int cur = t & 1, nxt = cur ^ 1;
    if (t + 1 < NTILE) {
      const short* sv = vfb + vbase + (size_t)(t + 1) * 4096 + wid4 * 1024 + lane * 8;
      rv0 = *(const bf16x8*)(sv);
      rv1 = *(const bf16x8*)(sv + 512);
      if (wid4 >= 2)
        rq = *(const bf16x8*)(ql + qbase + (size_t)(t + 1) * 1024 + (wid4 - 2) * 512 + lane * 8);
    }

    const short* vt = T + (grp * 2 + cur) * 4096;
    const short* qt = T + 16384 + (grp * 2 + cur) * 1024;

    bf16x8 qf0 = *(const bf16x8*)(qt + lane * 8);
    bf16x8 qf1 = *(const bf16x8*)(qt + 512 + lane * 8);
    f32x4 s0 = mfma16(qf0, kf, zf);
    f32x4 s1 = mfma16(qf1, kf, zf);

    float tm = fmaxf(fmaxf(fmaxf(s0[0], s0[1]), fmaxf(s0[2], s0[3])),
                     fmaxf(fmaxf(s1[0], s1[1]), fmaxf(s1[2], s1[3])));
    tm = fmaxf(tm, __shfl_xor(tm, 16, 64));
    tm = fmaxf(tm, __shfl_xor(tm, 32, 64));
    float mnew = fmaxf(mrow, tm);
    float scale = __expf(mrow - mnew);
    float p[8];
#pragma unroll
    for (int r = 0; r < 4; ++r) {
      p[r]     = __expf(s0[r] - mnew);
      p[4 + r] = __expf(s1[r] - mnew);
    }
    float ps = p[0] + p[1] + p[2] + p[3] + p[4] + p[5] + p[6] + p[7];
    ps += __shfl_xor(ps, 16, 64);
    ps += __shfl_xor(ps, 32, 64);
    lrow = lrow * scale + ps;
    mrow = mnew;

    bf16x8 pf;
#pragma unroll
    for (int r = 0; r < 8; ++r) pf[r] = f2bf(p[r]);

    float sc[4];
#pragma unroll
    for (int r = 0; r < 4; ++r) sc[r] = __shfl(scale, 4 * g + r, 64);
#pragma unroll
    for (int n = 0; n < 8; ++n) {
#pragma unroll
      for (int r = 0; r < 4; ++r) o[n][r] *= sc[r];
    }

#pragma unroll
    for (int n = 0; n < 8; ++n) {
      bf16x8 vfr = *(const bf16x8*)(vt + n * 512 + lane * 8);
      o[n] = mfma16(pf, vfr, o[n]);
    }

    if (t + 1 < NTILE) {
      short* vd = T + (grp * 2 + nxt) * 4096;
      *(bf16x8*)(vd + wid4 * 1024 + lane * 8) = rv0;
      *(bf16x8*)(vd + wid4 * 1024 + 512 + lane * 8) = rv1;
      if (wid4 >= 2) *(bf16x8*)(T + 16384 + (grp * 2 + nxt) * 1024 + (wid4 - 2) * 512 + lane * 8) = rq;
    }
    __syncthreads();
  }

  // ---- merge the two j-groups (max-aware), reusing the tile LDS ----
  float* O  = (float*)smem;        // [4][16][128] group-B o-partials (32 KB)
  float* MB = O + 8192;            // [4][16]
  float* LB = MB + 64;             // [4][16]
  if (grp == 1) {
    if (lane < 16) { MB[wid4 * 16 + lo] = mrow; LB[wid4 * 16 + lo] = lrow; }
#pragma unroll
    for (int n = 0; n < 8; ++n)
#pragma unroll
      for (int r = 0; r < 4; ++r)
        O[wid4 * 2048 + (4 * g + r) * 128 + n * 16 + lo] = o[n][r];
  }
  __syncthreads();
  if (grp == 0) {
    float mb = MB[wid4 * 16 + lo], lb = LB[wid4 * 16 + lo];
    float M  = fmaxf(mrow, mb);
    float eA = __expf(mrow - M), eB = __expf(mb - M);
    float linv = 1.f / (eA * lrow + eB * lb);
    float eAr[4], eBr[4], lir[4];
#pragma unroll
    for (int r = 0; r < 4; ++r) {
      int src = 4 * g + r;
      eAr[r] = __shfl(eA, src, 64);
      eBr[r] = __shfl(eB, src, 64);
      lir[r] = __shfl(linv, src, 64);
    }
#pragma unroll
    for (int n = 0; n < 8; ++n) {
      float bu = bias[n * 16 + lo];
#pragma unroll
      for (int r = 0; r < 4; ++r) {
        float s = eAr[r] * o[n][r] + eBr[r] * O[wid4 * 2048 + (4 * g + r) * 128 + n * 16 + lo];
        out[(size_t)(b * SEQ + iw + 4 * g + r) * OUTC + n * 16 + lo] = s * lir[r] + bu;
      }
    }
  }
}

// ---------------------------------------------------------------------------
extern "C" void kernel_launch(void* const* d_in, const int* in_sizes, int n_in,
                              void* d_out, int out_size, void* d_ws, size_t ws_size,
                              hipStream_t stream) {
  (void)in_sizes; (void)n_in; (void)out_size; (void)ws_size;
  const float* x      = (const float*)d_in[0];
  const float* weight = (const float*)d_in[1];
  const float* bias   = (const float*)d_in[2];
  const float* wq     = (const float*)d_in[3];
  const float* bq     = (const float*)d_in[4];
  const float* wk     = (const float*)d_in[5];
  const float* bk     = (const float*)d_in[6];
  const float* wv     = (const float*)d_in[7];
  const float* bv     = (const float*)d_in[8];
  float* out = (float*)d_out;

  char* ws = (char*)d_ws;
  short* kbuf = (short*)(ws);                                   // 1 MiB [p][32]
  short* vfb  = (short*)(ws + ((size_t)1 << 20));               // 4 MiB VF tiles
  short* qlb  = (short*)(ws + ((size_t)5 << 20));               // 1 MiB QL tiles
  short* wqb  = (short*)(ws + ((size_t)6 << 20));               // 8 KiB
  short* wkb  = (short*)(ws + ((size_t)6 << 20) + 8192);        // 8 KiB
  short* wfT  = (short*)(ws + ((size_t)6 << 20) + 16384);       // 32 KiB
  float* bfu  = (float*)(ws + ((size_t)6 << 20) + 49152);       // 512 B

  hipLaunchKernelGGL(k_fuse, dim3(OUTC), dim3(CIN), 0, stream,
                     wq, wk, wv, weight, bv, wqb, wkb, wfT, bfu);
  hipLaunchKernelGGL(k_proj, dim3(NB * SEQ / 64), dim3(256), 0, stream,
                     x, bq, bk, wqb, wkb, wfT, bfu, qlb, kbuf, vfb);
  hipLaunchKernelGGL(k_attn, dim3(NB * SEQ / 64), dim3(512), 0, stream,
                     qlb, kbuf, vfb, bias, out);
}

// Round 6
// 70.184 us; speedup vs baseline: 4.5286x; 1.1630x over previous
//
#include <hip/hip_runtime.h>

#define NB   4
#define SEQ  4096
#define CIN  128
#define C4D  32
#define OUTC 128
#define NTILE 64   // 32-j tiles per j-half (2048/32)

typedef __attribute__((ext_vector_type(8))) short bf16x8;
typedef __attribute__((ext_vector_type(4))) float f32x4;

__device__ __forceinline__ short f2bf(float f) {
  union { float f; unsigned u; } v; v.f = f;
  unsigned r = v.u + 0x7FFFu + ((v.u >> 16) & 1u);
  return (short)(r >> 16);
}

__device__ __forceinline__ unsigned cvt_pk_bf16(float lo, float hi) {
  unsigned r;
  asm("v_cvt_pk_bf16_f32 %0, %1, %2" : "=v"(r) : "v"(lo), "v"(hi));
  return r;
}

__device__ __forceinline__ f32x4 mfma16(bf16x8 a, bf16x8 b, f32x4 c) {
  return __builtin_amdgcn_mfma_f32_16x16x32_bf16(a, b, c, 0, 0, 0);
}

// ---------------------------------------------------------------------------
// Kernel 1: fold value-path weights (unchanged).
// ---------------------------------------------------------------------------
__global__ void k_fuse(const float* __restrict__ wq, const float* __restrict__ wk,
                       const float* __restrict__ wv, const float* __restrict__ weight,
                       const float* __restrict__ bv,
                       short* __restrict__ wqb, short* __restrict__ wkb,
                       short* __restrict__ wfT, float* __restrict__ bfu) {
  int u = blockIdx.x, c = threadIdx.x;
  float acc = 0.f;
  for (int o = 0; o < OUTC; ++o) acc += wv[o * CIN + c] * weight[o * OUTC + u];
  wfT[u * CIN + c] = f2bf(acc);
  if (u < C4D) {
    wqb[u * CIN + c] = f2bf(wq[u * CIN + c]);
    wkb[u * CIN + c] = f2bf(wk[u * CIN + c]);
  }
  if (c == 0) {
    float a = 0.f;
    for (int o = 0; o < OUTC; ++o) a += bv[o] * weight[o * OUTC + u];
    bfu[u] = a;
  }
}

// ---------------------------------------------------------------------------
// Kernel 2: projections (unchanged from R5). Fragment-linear QL / VF tiles.
// ---------------------------------------------------------------------------
__global__ __launch_bounds__(256) void k_proj(
    const float* __restrict__ x, const float* __restrict__ bq, const float* __restrict__ bk,
    const short* __restrict__ wqb, const short* __restrict__ wkb,
    const short* __restrict__ wfT, const float* __restrict__ bfu,
    short* __restrict__ ql, short* __restrict__ kb, short* __restrict__ vfb) {
  const int wid = threadIdx.x >> 6, lane = threadIdx.x & 63;
  const int lo = lane & 15, g = lane >> 4;
  const int p0 = blockIdx.x * 64 + wid * 16;

  f32x4 aq[2] = {}, ak[2] = {}, as_[8] = {};

#pragma unroll
  for (int kk = 0; kk < 4; ++kk) {
    const float* xp = x + (size_t)(p0 + lo) * CIN + kk * 32 + g * 8;
    float4 xa = *(const float4*)xp;
    float4 xb = *(const float4*)(xp + 4);
    bf16x8 af;
    af[0] = f2bf(xa.x); af[1] = f2bf(xa.y); af[2] = f2bf(xa.z); af[3] = f2bf(xa.w);
    af[4] = f2bf(xb.x); af[5] = f2bf(xb.y); af[6] = f2bf(xb.z); af[7] = f2bf(xb.w);
#pragma unroll
    for (int n = 0; n < 2; ++n) {
      bf16x8 bq_ = *(const bf16x8*)(wqb + (size_t)(n * 16 + lo) * CIN + kk * 32 + g * 8);
      aq[n] = mfma16(af, bq_, aq[n]);
      bf16x8 bk_ = *(const bf16x8*)(wkb + (size_t)(n * 16 + lo) * CIN + kk * 32 + g * 8);
      ak[n] = mfma16(af, bk_, ak[n]);
    }
#pragma unroll
    for (int n = 0; n < 8; ++n) {
      bf16x8 bs = *(const bf16x8*)(wfT + (size_t)(n * 16 + lo) * CIN + kk * 32 + g * 8);
      as_[n] = mfma16(af, bs, as_[n]);
    }
  }

#pragma unroll
  for (int n = 0; n < 2; ++n) {
    float bqv = bq[n * 16 + lo], bkv = bk[n * 16 + lo];
    int u = n * 16 + lo;
#pragma unroll
    for (int r = 0; r < 4; ++r) {
      int p = p0 + 4 * g + r;
      int bb = p >> 12, s = p & (SEQ - 1);
      ql[(size_t)bb * (SEQ * 32) + (size_t)(s >> 5) * 1024 + ((s >> 4) & 1) * 512 +
         (u >> 3) * 128 + (s & 15) * 8 + (u & 7)] = f2bf(aq[n][r] + bqv);
      kb[(size_t)p * C4D + u] = f2bf(ak[n][r] + bkv);
    }
  }
#pragma unroll
  for (int n = 0; n < 8; ++n) {
    int u = n * 16 + lo;
    float bvv = bfu[u];
#pragma unroll
    for (int r = 0; r < 4; ++r) {
      int p = p0 + 4 * g + r;
      int bb = p >> 12, s = p & (SEQ - 1);
      vfb[(size_t)bb * (SEQ * 128) + (size_t)(s >> 5) * 4096 + (u >> 4) * 512 +
          ((s >> 2) & 3) * 128 + (u & 15) * 8 + ((s >> 4) & 1) * 4 + (s & 3)] =
          f2bf(as_[n][r] + bvv);
    }
  }
}

// ---------------------------------------------------------------------------
// Kernel 3: attention. Structure = R5 (8 waves, 2 j-groups x 4 i-subs, LDS
// double-buffered fragment-linear tiles). Inner loop: defer-max softmax
// (THR=8, rescale ~1/64 iters), deferred l-reduce, cvt_pk P->bf16.
// ---------------------------------------------------------------------------
__global__ __launch_bounds__(512) void k_attn(
    const short* __restrict__ ql, const short* __restrict__ kb,
    const short* __restrict__ vfb, const float* __restrict__ bias,
    float* __restrict__ out) {
  const int tid = threadIdx.x;
  const int wid = tid >> 6, lane = tid & 63;
  const int lo = lane & 15, g = lane >> 4;
  const int wid4 = wid & 3, grp = wid >> 2;
  const int b = blockIdx.x >> 6;
  const int i0 = (blockIdx.x & 63) * 64;
  const int iw = i0 + wid4 * 16;

  __shared__ __align__(16) char smem[40960];
  short* T = (short*)smem;

  const size_t vbase = (size_t)b * (SEQ * 128) + (size_t)grp * (NTILE * 4096);
  const size_t qbase = (size_t)b * (SEQ * 32) + (size_t)grp * (NTILE * 1024);

  bf16x8 kf = *(const bf16x8*)(kb + (size_t)(b * SEQ + iw + lo) * C4D + g * 8);

  f32x4 o[8] = {};
  float mrow = -3e38f, lrow = 0.f, mthr = -3e38f;
  const f32x4 zf = {0.f, 0.f, 0.f, 0.f};

  bf16x8 rv0 = {}, rv1 = {}, rq = {};

  // prologue: stage tile 0
  {
    const short* sv = vfb + vbase + wid4 * 1024 + lane * 8;
    rv0 = *(const bf16x8*)(sv);
    rv1 = *(const bf16x8*)(sv + 512);
    if (wid4 >= 2) rq = *(const bf16x8*)(ql + qbase + (wid4 - 2) * 512 + lane * 8);
    short* vd = T + grp * 2 * 4096;
    *(bf16x8*)(vd + wid4 * 1024 + lane * 8) = rv0;
    *(bf16x8*)(vd + wid4 * 1024 + 512 + lane * 8) = rv1;
    if (wid4 >= 2) *(bf16x8*)(T + 16384 + grp * 2 * 1024 + (wid4 - 2) * 512 + lane * 8) = rq;
  }
  __syncthreads();

  for (int t = 0; t < NTILE; ++t) {
    const int cur = t & 1, nxt = cur ^ 1;
    if (t + 1 < NTILE) {
      const short* sv = vfb + vbase + (size_t)(t + 1) * 4096 + wid4 * 1024 + lane * 8;
      rv0 = *(const bf16x8*)(sv);
      rv1 = *(const bf16x8*)(sv + 512);
      if (wid4 >= 2)
        rq = *(const bf16x8*)(ql + qbase + (size_t)(t + 1) * 1024 + (wid4 - 2) * 512 + lane * 8);
    }

    const short* vt = T + (grp * 2 + cur) * 4096;
    const short* qt = T + 16384 + (grp * 2 + cur) * 1024;

    bf16x8 qf0 = *(const bf16x8*)(qt + lane * 8);
    bf16x8 qf1 = *(const bf16x8*)(qt + 512 + lane * 8);
    f32x4 s0 = mfma16(qf0, kf, zf);
    f32x4 s1 = mfma16(qf1, kf, zf);

    float tm = fmaxf(fmaxf(fmaxf(s0[0], s0[1]), fmaxf(s0[2], s0[3])),
                     fmaxf(fmaxf(s1[0], s1[1]), fmaxf(s1[2], s1[3])));
    if (__any(tm > mthr)) {   // rare: first tile + outlier growth only
      float rowm = fmaxf(tm, __shfl_xor(tm, 16, 64));
      rowm = fmaxf(rowm, __shfl_xor(rowm, 32, 64));
      float mnew = fmaxf(mrow, rowm);
      float scale = __expf(mrow - mnew);
      lrow *= scale;
      float sc[4];
#pragma unroll
      for (int r = 0; r < 4; ++r) sc[r] = __shfl(scale, 4 * g + r, 64);
#pragma unroll
      for (int n = 0; n < 8; ++n)
#pragma unroll
        for (int r = 0; r < 4; ++r) o[n][r] *= sc[r];
      mrow = mnew;
      mthr = mnew + 8.f;
    }

    float p[8];
#pragma unroll
    for (int r = 0; r < 4; ++r) {
      p[r]     = __expf(s0[r] - mrow);
      p[4 + r] = __expf(s1[r] - mrow);
    }
    lrow += (p[0] + p[1]) + (p[2] + p[3]) + ((p[4] + p[5]) + (p[6] + p[7]));

    union { bf16x8 v8; unsigned u[4]; } pk;
    pk.u[0] = cvt_pk_bf16(p[0], p[1]);
    pk.u[1] = cvt_pk_bf16(p[2], p[3]);
    pk.u[2] = cvt_pk_bf16(p[4], p[5]);
    pk.u[3] = cvt_pk_bf16(p[6], p[7]);
    bf16x8 pf = pk.v8;

#pragma unroll
    for (int n = 0; n < 8; ++n) {
      bf16x8 vfr = *(const bf16x8*)(vt + n * 512 + lane * 8);
      o[n] = mfma16(pf, vfr, o[n]);
    }

    if (t + 1 < NTILE) {
      short* vd = T + (grp * 2 + nxt) * 4096;
      *(bf16x8*)(vd + wid4 * 1024 + lane * 8) = rv0;
      *(bf16x8*)(vd + wid4 * 1024 + 512 + lane * 8) = rv1;
      if (wid4 >= 2) *(bf16x8*)(T + 16384 + (grp * 2 + nxt) * 1024 + (wid4 - 2) * 512 + lane * 8) = rq;
    }
    __syncthreads();
  }

  // deferred l-reduce across the 4 g-groups
  lrow += __shfl_xor(lrow, 16, 64);
  lrow += __shfl_xor(lrow, 32, 64);

  // ---- merge the two j-groups (max-aware), reusing the tile LDS ----
  float* O  = (float*)smem;        // [4][16][128] group-B o-partials (32 KB)
  float* MB = O + 8192;            // [4][16]
  float* LB = MB + 64;             // [4][16]
  if (grp == 1) {
    if (lane < 16) { MB[wid4 * 16 + lo] = mrow; LB[wid4 * 16 + lo] = lrow; }
#pragma unroll
    for (int n = 0; n < 8; ++n)
#pragma unroll
      for (int r = 0; r < 4; ++r)
        O[wid4 * 2048 + (4 * g + r) * 128 + n * 16 + lo] = o[n][r];
  }
  __syncthreads();
  if (grp == 0) {
    float mb = MB[wid4 * 16 + lo], lb = LB[wid4 * 16 + lo];
    float M  = fmaxf(mrow, mb);
    float eA = __expf(mrow - M), eB = __expf(mb - M);
    float linv = 1.f / (eA * lrow + eB * lb);
    float eAr[4], eBr[4], lir[4];
#pragma unroll
    for (int r = 0; r < 4; ++r) {
      int src = 4 * g + r;
      eAr[r] = __shfl(eA, src, 64);
      eBr[r] = __shfl(eB, src, 64);
      lir[r] = __shfl(linv, src, 64);
    }
#pragma unroll
    for (int n = 0; n < 8; ++n) {
      float bu = bias[n * 16 + lo];
#pragma unroll
      for (int r = 0; r < 4; ++r) {
        float s = eAr[r] * o[n][r] + eBr[r] * O[wid4 * 2048 + (4 * g + r) * 128 + n * 16 + lo];
        out[(size_t)(b * SEQ + iw + 4 * g + r) * OUTC + n * 16 + lo] = s * lir[r] + bu;
      }
    }
  }
}

// ---------------------------------------------------------------------------
extern "C" void kernel_launch(void* const* d_in, const int* in_sizes, int n_in,
                              void* d_out, int out_size, void* d_ws, size_t ws_size,
                              hipStream_t stream) {
  (void)in_sizes; (void)n_in; (void)out_size; (void)ws_size;
  const float* x      = (const float*)d_in[0];
  const float* weight = (const float*)d_in[1];
  const float* bias   = (const float*)d_in[2];
  const float* wq     = (const float*)d_in[3];
  const float* bq     = (const float*)d_in[4];
  const float* wk     = (const float*)d_in[5];
  const float* bk     = (const float*)d_in[6];
  const float* wv     = (const float*)d_in[7];
  const float* bv     = (const float*)d_in[8];
  float* out = (float*)d_out;

  char* ws = (char*)d_ws;
  short* kbuf = (short*)(ws);                                   // 1 MiB [p][32]
  short* vfb  = (short*)(ws + ((size_t)1 << 20));               // 4 MiB VF tiles
  short* qlb  = (short*)(ws + ((size_t)5 << 20));               // 1 MiB QL tiles
  short* wqb  = (short*)(ws + ((size_t)6 << 20));               // 8 KiB
  short* wkb  = (short*)(ws + ((size_t)6 << 20) + 8192);        // 8 KiB
  short* wfT  = (short*)(ws + ((size_t)6 << 20) + 16384);       // 32 KiB
  float* bfu  = (float*)(ws + ((size_t)6 << 20) + 49152);       // 512 B

  hipLaunchKernelGGL(k_fuse, dim3(OUTC), dim3(CIN), 0, stream,
                     wq, wk, wv, weight, bv, wqb, wkb, wfT, bfu);
  hipLaunchKernelGGL(k_proj, dim3(NB * SEQ / 64), dim3(256), 0, stream,
                     x, bq, bk, wqb, wkb, wfT, bfu, qlb, kbuf, vfb);
  hipLaunchKernelGGL(k_attn, dim3(NB * SEQ / 64), dim3(512), 0, stream,
                     qlb, kbuf, vfb, bias, out);
}

// Round 7
// 65.928 us; speedup vs baseline: 4.8210x; 1.0646x over previous
//
#include <hip/hip_runtime.h>

#define NB   4
#define SEQ  4096
#define CIN  128
#define C4D  32
#define OUTC 128

typedef __attribute__((ext_vector_type(8))) short bf16x8;
typedef __attribute__((ext_vector_type(4))) float f32x4;

__device__ __forceinline__ short f2bf(float f) {
  union { float f; unsigned u; } v; v.f = f;
  unsigned r = v.u + 0x7FFFu + ((v.u >> 16) & 1u);
  return (short)(r >> 16);
}

__device__ __forceinline__ unsigned cvt_pk_bf16(float lo, float hi) {
  unsigned r;
  asm("v_cvt_pk_bf16_f32 %0, %1, %2" : "=v"(r) : "v"(lo), "v"(hi));
  return r;
}

__device__ __forceinline__ f32x4 mfma16(bf16x8 a, bf16x8 b, f32x4 c) {
  return __builtin_amdgcn_mfma_f32_16x16x32_bf16(a, b, c, 0, 0, 0);
}

// ---------------------------------------------------------------------------
// Kernel 1: fold value-path weights (unchanged).
// ---------------------------------------------------------------------------
__global__ void k_fuse(const float* __restrict__ wq, const float* __restrict__ wk,
                       const float* __restrict__ wv, const float* __restrict__ weight,
                       const float* __restrict__ bv,
                       short* __restrict__ wqb, short* __restrict__ wkb,
                       short* __restrict__ wfT, float* __restrict__ bfu) {
  int u = blockIdx.x, c = threadIdx.x;
  float acc = 0.f;
  for (int o = 0; o < OUTC; ++o) acc += wv[o * CIN + c] * weight[o * OUTC + u];
  wfT[u * CIN + c] = f2bf(acc);
  if (u < C4D) {
    wqb[u * CIN + c] = f2bf(wq[u * CIN + c]);
    wkb[u * CIN + c] = f2bf(wk[u * CIN + c]);
  }
  if (c == 0) {
    float a = 0.f;
    for (int o = 0; o < OUTC; ++o) a += bv[o] * weight[o * OUTC + u];
    bfu[u] = a;
  }
}

// ---------------------------------------------------------------------------
// Kernel 2: projections (unchanged from R5). Fragment-linear QL / VF tiles.
// ---------------------------------------------------------------------------
__global__ __launch_bounds__(256) void k_proj(
    const float* __restrict__ x, const float* __restrict__ bq, const float* __restrict__ bk,
    const short* __restrict__ wqb, const short* __restrict__ wkb,
    const short* __restrict__ wfT, const float* __restrict__ bfu,
    short* __restrict__ ql, short* __restrict__ kb, short* __restrict__ vfb) {
  const int wid = threadIdx.x >> 6, lane = threadIdx.x & 63;
  const int lo = lane & 15, g = lane >> 4;
  const int p0 = blockIdx.x * 64 + wid * 16;

  f32x4 aq[2] = {}, ak[2] = {}, as_[8] = {};

#pragma unroll
  for (int kk = 0; kk < 4; ++kk) {
    const float* xp = x + (size_t)(p0 + lo) * CIN + kk * 32 + g * 8;
    float4 xa = *(const float4*)xp;
    float4 xb = *(const float4*)(xp + 4);
    bf16x8 af;
    af[0] = f2bf(xa.x); af[1] = f2bf(xa.y); af[2] = f2bf(xa.z); af[3] = f2bf(xa.w);
    af[4] = f2bf(xb.x); af[5] = f2bf(xb.y); af[6] = f2bf(xb.z); af[7] = f2bf(xb.w);
#pragma unroll
    for (int n = 0; n < 2; ++n) {
      bf16x8 bq_ = *(const bf16x8*)(wqb + (size_t)(n * 16 + lo) * CIN + kk * 32 + g * 8);
      aq[n] = mfma16(af, bq_, aq[n]);
      bf16x8 bk_ = *(const bf16x8*)(wkb + (size_t)(n * 16 + lo) * CIN + kk * 32 + g * 8);
      ak[n] = mfma16(af, bk_, ak[n]);
    }
#pragma unroll
    for (int n = 0; n < 8; ++n) {
      bf16x8 bs = *(const bf16x8*)(wfT + (size_t)(n * 16 + lo) * CIN + kk * 32 + g * 8);
      as_[n] = mfma16(af, bs, as_[n]);
    }
  }

#pragma unroll
  for (int n = 0; n < 2; ++n) {
    float bqv = bq[n * 16 + lo], bkv = bk[n * 16 + lo];
    int u = n * 16 + lo;
#pragma unroll
    for (int r = 0; r < 4; ++r) {
      int p = p0 + 4 * g + r;
      int bb = p >> 12, s = p & (SEQ - 1);
      ql[(size_t)bb * (SEQ * 32) + (size_t)(s >> 5) * 1024 + ((s >> 4) & 1) * 512 +
         (u >> 3) * 128 + (s & 15) * 8 + (u & 7)] = f2bf(aq[n][r] + bqv);
      kb[(size_t)p * C4D + u] = f2bf(ak[n][r] + bkv);
    }
  }
#pragma unroll
  for (int n = 0; n < 8; ++n) {
    int u = n * 16 + lo;
    float bvv = bfu[u];
#pragma unroll
    for (int r = 0; r < 4; ++r) {
      int p = p0 + 4 * g + r;
      int bb = p >> 12, s = p & (SEQ - 1);
      vfb[(size_t)bb * (SEQ * 128) + (size_t)(s >> 5) * 4096 + (u >> 4) * 512 +
          ((s >> 2) & 3) * 128 + (u & 15) * 8 + ((s >> 4) & 1) * 4 + (s & 3)] =
          f2bf(as_[n][r] + bvv);
    }
  }
}

// ---------------------------------------------------------------------------
// Kernel 3: attention, barrier-free main loop. Block = 8 waves, one 32-i-row
// unit; wave `wid` owns j-eighth [wid*512, (wid+1)*512). Q/V fragments read
// directly from global (fragment-linear, coalesced; L2-resident). Defer-max
// softmax, deferred l-reduce, cvt_pk. Tree merge via 2 LDS slots at the end.
// ---------------------------------------------------------------------------
__global__ __launch_bounds__(512, 4) void k_attn(
    const short* __restrict__ ql, const short* __restrict__ kb,
    const short* __restrict__ vfb, const float* __restrict__ bias,
    float* __restrict__ out) {
  const int tid = threadIdx.x;
  const int wid = tid >> 6, lane = tid & 63;
  const int lo = lane & 15, g = lane >> 4;
  const int b = blockIdx.x >> 7;
  const int iw = (blockIdx.x & 127) * 32;

  __shared__ float OS[2][4096];
  __shared__ float MS[2][32], LS[2][32];

  const short* qB = ql + (size_t)b * (SEQ * 32) + (size_t)wid * 16384;
  const short* vB = vfb + (size_t)b * (SEQ * 128) + (size_t)wid * 65536;

  bf16x8 kf0 = *(const bf16x8*)(kb + (size_t)(b * SEQ + iw + lo) * C4D + g * 8);
  bf16x8 kf1 = *(const bf16x8*)(kb + (size_t)(b * SEQ + iw + 16 + lo) * C4D + g * 8);

  f32x4 oa[8] = {}, ob[8] = {};
  float ma = -3e38f, mb_ = -3e38f, la = 0.f, lb = 0.f;
  float tha = -3e38f, thb = -3e38f;
  const f32x4 zf = {0.f, 0.f, 0.f, 0.f};

  for (int t = 0; t < 16; ++t) {
    const short* qt = qB + t * 1024;
    bf16x8 qf0 = *(const bf16x8*)(qt + lane * 8);
    bf16x8 qf1 = *(const bf16x8*)(qt + 512 + lane * 8);
    f32x4 sa0 = mfma16(qf0, kf0, zf);
    f32x4 sa1 = mfma16(qf1, kf0, zf);
    f32x4 sb0 = mfma16(qf0, kf1, zf);
    f32x4 sb1 = mfma16(qf1, kf1, zf);

    float tma = fmaxf(fmaxf(fmaxf(sa0[0], sa0[1]), fmaxf(sa0[2], sa0[3])),
                      fmaxf(fmaxf(sa1[0], sa1[1]), fmaxf(sa1[2], sa1[3])));
    float tmb = fmaxf(fmaxf(fmaxf(sb0[0], sb0[1]), fmaxf(sb0[2], sb0[3])),
                      fmaxf(fmaxf(sb1[0], sb1[1]), fmaxf(sb1[2], sb1[3])));
    if (__any((tma > tha) | (tmb > thb))) {
      float ra = fmaxf(tma, __shfl_xor(tma, 16, 64));
      ra = fmaxf(ra, __shfl_xor(ra, 32, 64));
      float rb = fmaxf(tmb, __shfl_xor(tmb, 16, 64));
      rb = fmaxf(rb, __shfl_xor(rb, 32, 64));
      float mna = fmaxf(ma, ra), mnb = fmaxf(mb_, rb);
      float sca = __expf(ma - mna), scb = __expf(mb_ - mnb);
      la *= sca; lb *= scb;
      float sra[4], srb[4];
#pragma unroll
      for (int r = 0; r < 4; ++r) {
        sra[r] = __shfl(sca, 4 * g + r, 64);
        srb[r] = __shfl(scb, 4 * g + r, 64);
      }
#pragma unroll
      for (int n = 0; n < 8; ++n)
#pragma unroll
        for (int r = 0; r < 4; ++r) { oa[n][r] *= sra[r]; ob[n][r] *= srb[r]; }
      ma = mna; mb_ = mnb; tha = ma + 8.f; thb = mb_ + 8.f;
    }

    float pa[8], pb[8];
#pragma unroll
    for (int r = 0; r < 4; ++r) {
      pa[r] = __expf(sa0[r] - ma); pa[4 + r] = __expf(sa1[r] - ma);
      pb[r] = __expf(sb0[r] - mb_); pb[4 + r] = __expf(sb1[r] - mb_);
    }
    la += (pa[0] + pa[1]) + (pa[2] + pa[3]) + ((pa[4] + pa[5]) + (pa[6] + pa[7]));
    lb += (pb[0] + pb[1]) + (pb[2] + pb[3]) + ((pb[4] + pb[5]) + (pb[6] + pb[7]));

    union { bf16x8 v8; unsigned u[4]; } ka, kb2;
    ka.u[0] = cvt_pk_bf16(pa[0], pa[1]); ka.u[1] = cvt_pk_bf16(pa[2], pa[3]);
    ka.u[2] = cvt_pk_bf16(pa[4], pa[5]); ka.u[3] = cvt_pk_bf16(pa[6], pa[7]);
    kb2.u[0] = cvt_pk_bf16(pb[0], pb[1]); kb2.u[1] = cvt_pk_bf16(pb[2], pb[3]);
    kb2.u[2] = cvt_pk_bf16(pb[4], pb[5]); kb2.u[3] = cvt_pk_bf16(pb[6], pb[7]);
    bf16x8 pfa = ka.v8, pfb = kb2.v8;

    const short* vt = vB + t * 4096;
#pragma unroll
    for (int n = 0; n < 8; ++n) {
      bf16x8 vfr = *(const bf16x8*)(vt + n * 512 + lane * 8);
      oa[n] = mfma16(pfa, vfr, oa[n]);
      ob[n] = mfma16(pfb, vfr, ob[n]);
    }
  }

  // deferred l-reduce over g-groups -> per-row totals (uniform in g)
  la += __shfl_xor(la, 16, 64); la += __shfl_xor(la, 32, 64);
  lb += __shfl_xor(lb, 16, 64); lb += __shfl_xor(lb, 32, 64);

  auto write_slot = [&](int s) {
#pragma unroll
    for (int n = 0; n < 8; ++n) {
      *(f32x4*)&OS[s][n * 256 + lane * 4] = oa[n];
      *(f32x4*)&OS[s][(8 + n) * 256 + lane * 4] = ob[n];
    }
    if (lane < 16) {
      MS[s][lo] = ma; MS[s][16 + lo] = mb_;
      LS[s][lo] = la; LS[s][16 + lo] = lb;
    }
  };
  auto merge_slot = [&](int s) {
    float msa = MS[s][lo], msb = MS[s][16 + lo];
    float lsa = LS[s][lo], lsb = LS[s][16 + lo];
    float Ma = fmaxf(ma, msa), Mb = fmaxf(mb_, msb);
    float eoa = __expf(ma - Ma), esa = __expf(msa - Ma);
    float eob = __expf(mb_ - Mb), esb = __expf(msb - Mb);
    la = eoa * la + esa * lsa; lb = eob * lb + esb * lsb;
    ma = Ma; mb_ = Mb; tha = ma + 8.f; thb = mb_ + 8.f;
    float eoar[4], esar[4], eobr[4], esbr[4];
#pragma unroll
    for (int r = 0; r < 4; ++r) {
      int src = 4 * g + r;
      eoar[r] = __shfl(eoa, src, 64); esar[r] = __shfl(esa, src, 64);
      eobr[r] = __shfl(eob, src, 64); esbr[r] = __shfl(esb, src, 64);
    }
#pragma unroll
    for (int n = 0; n < 8; ++n) {
      f32x4 va = *(f32x4*)&OS[s][n * 256 + lane * 4];
      f32x4 vb = *(f32x4*)&OS[s][(8 + n) * 256 + lane * 4];
#pragma unroll
      for (int r = 0; r < 4; ++r) {
        oa[n][r] = eoar[r] * oa[n][r] + esar[r] * va[r];
        ob[n][r] = eobr[r] * ob[n][r] + esbr[r] * vb[r];
      }
    }
  };

  if (wid == 1) write_slot(0);
  if (wid == 3) write_slot(1);
  __syncthreads();
  if (wid == 0) merge_slot(0);
  if (wid == 2) merge_slot(1);
  __syncthreads();
  if (wid == 5) write_slot(0);
  if (wid == 7) write_slot(1);
  __syncthreads();
  if (wid == 4) merge_slot(0);
  if (wid == 6) merge_slot(1);
  __syncthreads();
  if (wid == 2) write_slot(0);
  if (wid == 6) write_slot(1);
  __syncthreads();
  if (wid == 0) merge_slot(0);
  if (wid == 4) merge_slot(1);
  __syncthreads();
  if (wid == 4) write_slot(0);
  __syncthreads();
  if (wid == 0) {
    merge_slot(0);
    float lia[4], lib[4];
    float ia = 1.f / la, ib = 1.f / lb;
#pragma unroll
    for (int r = 0; r < 4; ++r) {
      int src = 4 * g + r;
      lia[r] = __shfl(ia, src, 64);
      lib[r] = __shfl(ib, src, 64);
    }
    float* outp = out + (size_t)(b * SEQ + iw) * OUTC;
#pragma unroll
    for (int n = 0; n < 8; ++n) {
      float bu = bias[n * 16 + lo];
#pragma unroll
      for (int r = 0; r < 4; ++r) {
        outp[(size_t)(4 * g + r) * OUTC + n * 16 + lo] = oa[n][r] * lia[r] + bu;
        outp[(size_t)(16 + 4 * g + r) * OUTC + n * 16 + lo] = ob[n][r] * lib[r] + bu;
      }
    }
  }
}

// ---------------------------------------------------------------------------
extern "C" void kernel_launch(void* const* d_in, const int* in_sizes, int n_in,
                              void* d_out, int out_size, void* d_ws, size_t ws_size,
                              hipStream_t stream) {
  (void)in_sizes; (void)n_in; (void)out_size; (void)ws_size;
  const float* x      = (const float*)d_in[0];
  const float* weight = (const float*)d_in[1];
  const float* bias   = (const float*)d_in[2];
  const float* wq     = (const float*)d_in[3];
  const float* bq     = (const float*)d_in[4];
  const float* wk     = (const float*)d_in[5];
  const float* bk     = (const float*)d_in[6];
  const float* wv     = (const float*)d_in[7];
  const float* bv     = (const float*)d_in[8];
  float* out = (float*)d_out;

  char* ws = (char*)d_ws;
  short* kbuf = (short*)(ws);                                   // 1 MiB [p][32]
  short* vfb  = (short*)(ws + ((size_t)1 << 20));               // 4 MiB VF tiles
  short* qlb  = (short*)(ws + ((size_t)5 << 20));               // 1 MiB QL tiles
  short* wqb  = (short*)(ws + ((size_t)6 << 20));               // 8 KiB
  short* wkb  = (short*)(ws + ((size_t)6 << 20) + 8192);        // 8 KiB
  short* wfT  = (short*)(ws + ((size_t)6 << 20) + 16384);       // 32 KiB
  float* bfu  = (float*)(ws + ((size_t)6 << 20) + 49152);       // 512 B

  hipLaunchKernelGGL(k_fuse, dim3(OUTC), dim3(CIN), 0, stream,
                     wq, wk, wv, weight, bv, wqb, wkb, wfT, bfu);
  hipLaunchKernelGGL(k_proj, dim3(NB * SEQ / 64), dim3(256), 0, stream,
                     x, bq, bk, wqb, wkb, wfT, bfu, qlb, kbuf, vfb);
  hipLaunchKernelGGL(k_attn, dim3(NB * SEQ / 32), dim3(512), 0, stream,
                     qlb, kbuf, vfb, bias, out);
}